// Round 9
// baseline (122.476 us; speedup 1.0000x reference)
//
#include <hip/hip_runtime.h>

typedef short bf16x8 __attribute__((ext_vector_type(8)));
typedef float f32x4 __attribute__((ext_vector_type(4)));
typedef unsigned short u16;

__device__ __forceinline__ u16 f2bf(float f) {
    unsigned u = __builtin_bit_cast(unsigned, f);
    u += 0x7FFF + ((u >> 16) & 1);
    return (u16)(u >> 16);
}

// Problem dims
constexpr int Hh = 64, Ww = 64, Ci = 128;
constexpr int Fo = 256, OH = 62, OW = 62;
constexpr int Ktot = 3 * 3 * Ci;      // 1152
constexpr int M_TOT = 123008;         // 32*62*62
constexpr int BM = 256, BK = 64;      // BN = 256 (full N)
constexpr int NSTEP = Ktot / BK;      // 18
constexpr int NWG = 481;              // ceil(123008/256)
constexpr long NEL_IN = 32L * 64 * 64 * 128;
constexpr size_t WS_IN_BYTES = (size_t)NEL_IN * 2;  // 33,554,432
constexpr size_t WS_WT_OFF   = WS_IN_BYTES;
constexpr size_t WS_NEED     = WS_IN_BYTES + 294912ull * 2;

#define GLD_LDS(src, dst) __builtin_amdgcn_global_load_lds( \
    (const __attribute__((address_space(1))) unsigned int*)(src), \
    (__attribute__((address_space(3))) unsigned int*)(dst), 16, 0, 0)
#define MEMFENCE asm volatile("" ::: "memory")

// ---- pre-pass: fp32 input -> bf16 ----
__global__ __launch_bounds__(256) void cvt_input(const float* __restrict__ in,
                                                 u16* __restrict__ ob) {
    const int i = blockIdx.x * 256 + threadIdx.x;
    const float4* s = (const float4*)in + (long)i * 2;
    float4 v0 = s[0], v1 = s[1];
    bf16x8 p;
    p[0] = (short)f2bf(v0.x); p[1] = (short)f2bf(v0.y);
    p[2] = (short)f2bf(v0.z); p[3] = (short)f2bf(v0.w);
    p[4] = (short)f2bf(v1.x); p[5] = (short)f2bf(v1.y);
    p[6] = (short)f2bf(v1.z); p[7] = (short)f2bf(v1.w);
    ((bf16x8*)ob)[i] = p;
}

// ---- pre-pass: wt [k=1152][f=256] fp32 -> [f=256][k=1152] bf16 ----
__global__ __launch_bounds__(256) void cvt_wt(const float* __restrict__ wt,
                                              u16* __restrict__ ob) {
    const int t = blockIdx.x * 256 + threadIdx.x;   // 0 .. 36863
    const int f = t / 144, k8 = t % 144;
    bf16x8 p;
    #pragma unroll
    for (int j = 0; j < 8; ++j)
        p[j] = (short)f2bf(wt[(k8 * 8 + j) * Fo + f]);
    ((bf16x8*)ob)[f * 144 + k8] = p;
}

// ---- main: 256x256 tile, 8-phase-style fine interleave (4 phases/K-tile) ----
__global__ __launch_bounds__(512) void conv_mfma(
    const u16* __restrict__ inb,   // bf16 [32][64][64][128]
    const u16* __restrict__ wtb,   // bf16 [256][1152]
    float* __restrict__ out)       // [123008][256] fp32, r=(oh*62+ow)*32+b
{
    // [tile parity][half][128 rows][64 k] bf16 = 16 KB per slot, 128 KB total
    __shared__ __align__(16) short As[2][2][128 * 64];
    __shared__ __align__(16) short Bs[2][2][128 * 64];

    const int tid  = threadIdx.x;
    const int lane = tid & 63;
    const int wv   = tid >> 6;               // 0..7
    const int wr   = wv >> 2, wc = wv & 3;   // wave rows: {wr*64..}+{128+wr*64..}; cols: {wc*32..}+{128+wc*32..}

    // bijective XCD swizzle (481: q=60, rr=1)
    constexpr int q = NWG / 8, rr = NWG % 8;
    const int orig = blockIdx.x;
    const int xcd = orig & 7, idx = orig >> 3;
    const int wgid = (xcd < rr ? xcd * (q + 1) : rr * (q + 1) + (xcd - rr) * q) + idx;
    const int r0 = wgid * BM;

    // ---- staging addresses: half-tile = 128 rows x 128 B; per wave 2 gld_lds
    // (local rows wv*16+j*8 .. +7). Pre-swizzled source chunk (l&7)^(l>>3):
    // LDS chunk c of local row r holds global chunk c^(r&7); reads XOR same.
    const int lrow8 = lane >> 3;
    const int schunk = ((lane & 7) ^ lrow8) * 16;
    long abyte[2][2], bbyte[2][2];
    #pragma unroll
    for (int h = 0; h < 2; ++h)
        #pragma unroll
        for (int j = 0; j < 2; ++j) {
            int r = r0 + h * 128 + wv * 16 + j * 8 + lrow8;
            r = r < M_TOT ? r : M_TOT - 1;   // clamp (last block)
            const int bb = r & 31;
            const int pix = r >> 5;
            const int ow = pix % OW, oh = pix / OW;
            abyte[h][j] = (long)(((bb * Hh + oh) * Ww + ow) * Ci) * 2 + schunk;
            const int f = h * 128 + wv * 16 + j * 8 + lrow8;
            bbyte[h][j] = (long)f * (Ktot * 2) + schunk;
        }

    auto stageA = [&](int tt, int h) {
        const int kb = tt >> 1, c0 = (tt & 1) << 6;
        const int kh = kb / 3, kw = kb % 3;
        const long tap = (long)((kh * Ww + kw) * Ci + c0) * 2;
        #pragma unroll
        for (int j = 0; j < 2; ++j)
            GLD_LDS((const char*)inb + abyte[h][j] + tap, &As[tt & 1][h][(wv * 16 + j * 8) * 64]);
    };
    auto stageB = [&](int tt, int h) {
        const long bof = (long)tt * 128;
        #pragma unroll
        for (int j = 0; j < 2; ++j)
            GLD_LDS((const char*)wtb + bbyte[h][j] + bof, &Bs[tt & 1][h][(wv * 16 + j * 8) * 64]);
    };

    f32x4 acc[2][2][4][2];   // [mh][nh][m][n]
    #pragma unroll
    for (int i1 = 0; i1 < 2; ++i1)
        #pragma unroll
        for (int i2 = 0; i2 < 2; ++i2)
            #pragma unroll
            for (int m = 0; m < 4; ++m)
                #pragma unroll
                for (int n = 0; n < 2; ++n)
                    acc[i1][i2][m][n] = (f32x4){0.f, 0.f, 0.f, 0.f};

    const int lrow = lane & 15;
    const int lq   = lane >> 4;

    // ---- prologue: virtual phases P3(-2)..P4(-1) of the stage schedule ----
    stageA(0, 0); stageB(0, 0);            // P3(-2), P4(-2)
    stageB(0, 1); stageA(0, 1);            // P1(-1), P2(-1)
    stageA(1, 0); stageB(1, 0);            // P3(-1), P4(-1)
    asm volatile("s_waitcnt vmcnt(4)" ::: "memory");   // tile 0 fully landed
    MEMFENCE;
    __builtin_amdgcn_s_barrier();
    MEMFENCE;

    // One phase: 12 ds_read_b128 + stage + barrier + lgkmcnt(0) + 16 MFMA + barrier
#define PHASE(CB, MH, NH, STAGE_CODE, VWAIT_CODE) {                              \
        const char* Ab = (const char*)&As[CB][MH][0];                            \
        const char* Bb = (const char*)&Bs[CB][NH][0];                            \
        bf16x8 av[4][2], bv[2][2];                                               \
        _Pragma("unroll")                                                        \
        for (int m = 0; m < 4; ++m) {                                            \
            const int lr = wr * 64 + m * 16 + lrow;                              \
            _Pragma("unroll")                                                    \
            for (int ks = 0; ks < 2; ++ks)                                       \
                av[m][ks] = *(const bf16x8*)(Ab + lr * 128 +                     \
                    ((ks * 64 + lq * 16) ^ ((lr & 7) << 4)));                    \
        }                                                                        \
        _Pragma("unroll")                                                        \
        for (int n = 0; n < 2; ++n) {                                            \
            const int fr = wc * 32 + n * 16 + lrow;                              \
            _Pragma("unroll")                                                    \
            for (int ks = 0; ks < 2; ++ks)                                       \
                bv[n][ks] = *(const bf16x8*)(Bb + fr * 128 +                     \
                    ((ks * 64 + lq * 16) ^ ((fr & 7) << 4)));                    \
        }                                                                        \
        STAGE_CODE;                                                              \
        asm volatile("s_waitcnt lgkmcnt(8)" ::: "memory");                       \
        MEMFENCE;                                                                \
        __builtin_amdgcn_s_barrier();                                            \
        asm volatile("s_waitcnt lgkmcnt(0)" ::: "memory");                       \
        __builtin_amdgcn_sched_barrier(0);                                       \
        __builtin_amdgcn_s_setprio(1);                                           \
        _Pragma("unroll")                                                        \
        for (int ks = 0; ks < 2; ++ks)                                           \
            _Pragma("unroll")                                                    \
            for (int m = 0; m < 4; ++m)                                          \
                _Pragma("unroll")                                                \
                for (int n = 0; n < 2; ++n)                                      \
                    acc[MH][NH][m][n] = __builtin_amdgcn_mfma_f32_16x16x32_bf16( \
                        av[m][ks], bv[n][ks], acc[MH][NH][m][n], 0, 0, 0);       \
        __builtin_amdgcn_s_setprio(0);                                           \
        VWAIT_CODE;                                                              \
        MEMFENCE;                                                                \
        __builtin_amdgcn_s_barrier();                                            \
        MEMFENCE;                                                                \
    }

    for (int t = 0; t < NSTEP; ++t) {
        const int cb = t & 1;
        const bool s1 = (t + 1 < NSTEP), s2 = (t + 2 < NSTEP);
        // P1 (mh0,nh0): stage B-half1(t+1) -> Bs[cb^1][1] (freed end P4(t-1))
        PHASE(cb, 0, 0, { if (s1) stageB(t + 1, 1); }, {});
        // P2 (mh0,nh1): stage A-half1(t+1) -> As[cb^1][1] (freed end P4(t-1))
        PHASE(cb, 0, 1, { if (s1) stageA(t + 1, 1); }, {});
        // P3 (mh1,nh0): stage A-half0(t+2) -> As[cb][0] (freed end P2(t))
        PHASE(cb, 1, 0, { if (s2) stageA(t + 2, 0); }, {});
        // P4 (mh1,nh1): stage B-half0(t+2) -> Bs[cb][0] (freed end P3(t));
        // counted vmcnt: leaves only {A0(t+1),B0(t+1)} uncertified (unused in tile t+1's entry reads? they ARE tile t+1's P1 reads -> certified next P4... no: they are certified HERE next iteration). Ledger verified in analysis.
        PHASE(cb, 1, 1, { if (s2) stageB(t + 2, 0); },
              { if (s2) { asm volatile("s_waitcnt vmcnt(4)" ::: "memory"); }
                else if (s1) { asm volatile("s_waitcnt vmcnt(0)" ::: "memory"); } });
    }
#undef PHASE

    // ---- epilogue: relu + store ----
    const int lcol = lane & 15;
    const int lr4  = (lane >> 4) * 4;
    if (r0 + BM <= M_TOT) {
        #pragma unroll
        for (int mh = 0; mh < 2; ++mh)
            #pragma unroll
            for (int m = 0; m < 4; ++m) {
                const int rowbase = r0 + mh * 128 + wr * 64 + m * 16 + lr4;
                #pragma unroll
                for (int nh = 0; nh < 2; ++nh)
                    #pragma unroll
                    for (int n = 0; n < 2; ++n) {
                        const int col = nh * 128 + wc * 32 + n * 16 + lcol;
                        #pragma unroll
                        for (int e = 0; e < 4; ++e) {
                            float v = acc[mh][nh][m][n][e];
                            out[(long)(rowbase + e) * Fo + col] = v > 0.f ? v : 0.f;
                        }
                    }
            }
    } else {
        #pragma unroll
        for (int mh = 0; mh < 2; ++mh)
            #pragma unroll
            for (int m = 0; m < 4; ++m) {
                const int rowbase = r0 + mh * 128 + wr * 64 + m * 16 + lr4;
                #pragma unroll
                for (int nh = 0; nh < 2; ++nh)
                    #pragma unroll
                    for (int n = 0; n < 2; ++n) {
                        const int col = nh * 128 + wc * 32 + n * 16 + lcol;
                        #pragma unroll
                        for (int e = 0; e < 4; ++e) {
                            if (rowbase + e < M_TOT) {
                                float v = acc[mh][nh][m][n][e];
                                out[(long)(rowbase + e) * Fo + col] = v > 0.f ? v : 0.f;
                            }
                        }
                    }
            }
    }
}

// ================== fallback (round-2 proven kernel, no workspace) ==================
__global__ __launch_bounds__(256) void conv_mfma_fb(
    const float* __restrict__ in, const float* __restrict__ wt,
    float* __restrict__ out)
{
    __shared__ __align__(16) short As[128 * BK];
    __shared__ __align__(16) short Bs[128 * BK];
    const int tid  = threadIdx.x;
    const int lane = tid & 63;
    const int wv   = tid >> 6;
    const int wr   = wv >> 1, wc = wv & 1;
    constexpr int NWG_FB = 1922;
    constexpr int q2 = NWG_FB / 8, rr2 = NWG_FB % 8;
    const int orig = blockIdx.x;
    const int xcd = orig & 7, idx = orig >> 3;
    const int wgid = (xcd < rr2 ? xcd * (q2 + 1) : rr2 * (q2 + 1) + (xcd - rr2) * q2) + idx;
    const int colb = wgid & 1;
    const int rowb = wgid >> 1;
    const int r0   = rowb * 128;
    const int f0g  = colb * 128;
    const int ai = tid >> 1;
    const int ah = tid & 1;
    const int r  = r0 + ai;
    const int bb  = r & 31;
    const int pix = r >> 5;
    const int ow  = pix % OW;
    const int oh  = pix / OW;
    const float* abase = in + ((bb * Hh + oh) * Ww + ow) * Ci;
    const int bk = tid & 63;
    const int bf = (tid >> 6) * 32;

    auto loadA = [&](int step, float4 (&pa)[8]) {
        const int kb = step >> 1;
        const int c0 = (step & 1) << 6;
        const int kh = kb / 3, kw = kb % 3;
        const float* src = abase + (kh * Ww + kw) * Ci + c0 + ah * 32;
        #pragma unroll
        for (int c = 0; c < 8; ++c) pa[c] = ((const float4*)src)[c];
    };
    auto writeA = [&](const float4 (&pa)[8]) {
        char* dst = (char*)As + ai * 128;
        const int swz = (ai & 7) << 4;
        #pragma unroll
        for (int c = 0; c < 4; ++c) {
            float4 v0 = pa[2 * c], v1 = pa[2 * c + 1];
            bf16x8 pk;
            pk[0] = (short)f2bf(v0.x); pk[1] = (short)f2bf(v0.y);
            pk[2] = (short)f2bf(v0.z); pk[3] = (short)f2bf(v0.w);
            pk[4] = (short)f2bf(v1.x); pk[5] = (short)f2bf(v1.y);
            pk[6] = (short)f2bf(v1.z); pk[7] = (short)f2bf(v1.w);
            *(bf16x8*)(dst + ((ah * 64 + c * 16) ^ swz)) = pk;
        }
    };
    auto loadB = [&](int step, float4 (&pb)[8]) {
        const float* src = wt + (step * BK + bk) * Fo + f0g + bf;
        #pragma unroll
        for (int c = 0; c < 8; ++c) pb[c] = ((const float4*)src)[c];
    };
    auto writeB = [&](const float4 (&pb)[8]) {
        const int k2 = bk * 2;
        #pragma unroll
        for (int c = 0; c < 8; ++c) {
            float4 v = pb[c];
            const int fl = bf + c * 4;
            *(u16*)((char*)Bs + (fl + 0) * 128 + (k2 ^ (((fl + 0) & 7) << 4))) = f2bf(v.x);
            *(u16*)((char*)Bs + (fl + 1) * 128 + (k2 ^ (((fl + 1) & 7) << 4))) = f2bf(v.y);
            *(u16*)((char*)Bs + (fl + 2) * 128 + (k2 ^ (((fl + 2) & 7) << 4))) = f2bf(v.z);
            *(u16*)((char*)Bs + (fl + 3) * 128 + (k2 ^ (((fl + 3) & 7) << 4))) = f2bf(v.w);
        }
    };

    f32x4 acc[4][4];
    #pragma unroll
    for (int m = 0; m < 4; ++m)
        #pragma unroll
        for (int n = 0; n < 4; ++n) acc[m][n] = (f32x4){0.f, 0.f, 0.f, 0.f};
    {
        float4 pa[8], pb[8];
        loadA(0, pa); loadB(0, pb);
        writeA(pa); writeB(pb);
    }
    __syncthreads();
    const int lrow = lane & 15;
    const int lq   = lane >> 4;
    for (int step = 0; step < NSTEP; ++step) {
        float4 na[8], nb[8];
        if (step + 1 < NSTEP) { loadA(step + 1, na); loadB(step + 1, nb); }
        #pragma unroll
        for (int ks = 0; ks < 2; ++ks) {
            bf16x8 a[4], b[4];
            const int off = ks * 64 + lq * 16;
            #pragma unroll
            for (int m = 0; m < 4; ++m) {
                const int row = wr * 64 + m * 16 + lrow;
                a[m] = *(const bf16x8*)((const char*)As + row * 128 + (off ^ ((row & 7) << 4)));
            }
            #pragma unroll
            for (int n = 0; n < 4; ++n) {
                const int row = wc * 64 + n * 16 + lrow;
                b[n] = *(const bf16x8*)((const char*)Bs + row * 128 + (off ^ ((row & 7) << 4)));
            }
            #pragma unroll
            for (int m = 0; m < 4; ++m)
                #pragma unroll
                for (int n = 0; n < 4; ++n)
                    acc[m][n] = __builtin_amdgcn_mfma_f32_16x16x32_bf16(a[m], b[n], acc[m][n], 0, 0, 0);
        }
        __syncthreads();
        if (step + 1 < NSTEP) { writeA(na); writeB(nb); }
        __syncthreads();
    }
    const int lcol = lane & 15;
    const int lr4  = (lane >> 4) * 4;
    #pragma unroll
    for (int m = 0; m < 4; ++m) {
        #pragma unroll
        for (int n = 0; n < 4; ++n) {
            const int col = f0g + wc * 64 + n * 16 + lcol;
            const int rowbase = r0 + wr * 64 + m * 16 + lr4;
            #pragma unroll
            for (int e = 0; e < 4; ++e) {
                float v = acc[m][n][e];
                out[(rowbase + e) * Fo + col] = v > 0.f ? v : 0.f;
            }
        }
    }
}

extern "C" void kernel_launch(void* const* d_in, const int* in_sizes, int n_in,
                              void* d_out, int out_size, void* d_ws, size_t ws_size,
                              hipStream_t stream) {
    const float* in  = (const float*)d_in[0];
    const float* wt  = (const float*)d_in[1];
    float* out = (float*)d_out;
    if (ws_size >= WS_NEED) {
        u16* inb = (u16*)d_ws;
        u16* wtb = (u16*)((char*)d_ws + WS_WT_OFF);
        cvt_input<<<dim3(8192), dim3(256), 0, stream>>>(in, inb);
        cvt_wt<<<dim3(144), dim3(256), 0, stream>>>(wt, wtb);
        conv_mfma<<<dim3(NWG), dim3(512), 0, stream>>>(inb, wtb, out);
    } else {
        conv_mfma_fb<<<dim3(1922), dim3(256), 0, stream>>>(in, wt, out);
    }
}